// Round 7
// baseline (173.708 us; speedup 1.0000x reference)
//
#include <hip/hip_runtime.h>

#define NBLOCKS 2048
#define NTHREADS 256

// Per-sample loss. DELTA = 1.0, CENSORING_WEIGHT = 1.0.
__device__ __forceinline__ float per_sample(float pe, float ps, float tg,
                                            float th, int bid, int cen) {
  float pred = (bid == 0) ? pe : ps;
  float d = fmaxf(th - pred, 0.0f);
  float closs = d * d;
  float ae = fabsf(pred - tg);
  float q = fminf(ae, 1.0f);
  float hub = 0.5f * q * q + (ae - q);
  return cen ? closs : hub;
}

__device__ __forceinline__ float proc4(const float4& e, const float4& s,
                                       const float4& t, const float4& h,
                                       const int4& b, int c0, int c1, int c2,
                                       int c3) {
  float a = per_sample(e.x, s.x, t.x, h.x, b.x, c0);
  a += per_sample(e.y, s.y, t.y, h.y, b.y, c1);
  a += per_sample(e.z, s.z, t.z, h.z, b.z, c2);
  a += per_sample(e.w, s.w, t.w, h.w, b.w, c3);
  return a;
}

// R5's proven main loop (2048 chunked blocks, unroll-4 ARRAY-MAJOR groups at
// stride NTHREADS => lane-contiguous 1KB segments per load, 4KB burst per
// array per group). R6 lesson: thread-consecutive float4 pairs break
// per-instruction coalescing (-40%). Only change vs R5: fused ticket tail.
__global__ __launch_bounds__(NTHREADS, 4) void dualhead_fused(
    const float4* __restrict__ pe, const float4* __restrict__ ps,
    const float4* __restrict__ tg, const int4* __restrict__ bid,
    const void* __restrict__ cens, const float4* __restrict__ th,
    float* __restrict__ partials, unsigned* __restrict__ counter,
    float* __restrict__ out, int nvec, double inv_n) {
  // Layout probe (proven R3-R6): int32 {0,1} => high 3 bytes of dword are 0.
  unsigned probe = ((const unsigned*)cens)[threadIdx.x & 63];
  const bool is8 = __ballot((probe & 0xFFFFFF00u) != 0) != 0ULL;

  const int vpb = nvec / gridDim.x;  // vec4 elems per block (2048 for N=16M)
  const int base = blockIdx.x * vpb;
  const int end = base + vpb;
  float acc = 0.0f;
  int i = base + threadIdx.x;

  // Unroll-4 group: 24 loads in flight, 4KB contiguity per array.
  for (; i + 3 * NTHREADS < end; i += 4 * NTHREADS) {
    const int i0 = i, i1 = i + NTHREADS, i2 = i + 2 * NTHREADS,
              i3 = i + 3 * NTHREADS;
    float4 e0 = pe[i0], e1 = pe[i1], e2 = pe[i2], e3 = pe[i3];
    float4 s0 = ps[i0], s1 = ps[i1], s2 = ps[i2], s3 = ps[i3];
    float4 t0 = tg[i0], t1 = tg[i1], t2 = tg[i2], t3 = tg[i3];
    float4 h0 = th[i0], h1 = th[i1], h2 = th[i2], h3 = th[i3];
    int4 b0 = bid[i0], b1 = bid[i1], b2 = bid[i2], b3 = bid[i3];
    if (is8) {
      uchar4 c0 = ((const uchar4*)cens)[i0];
      uchar4 c1 = ((const uchar4*)cens)[i1];
      uchar4 c2 = ((const uchar4*)cens)[i2];
      uchar4 c3 = ((const uchar4*)cens)[i3];
      acc += proc4(e0, s0, t0, h0, b0, c0.x, c0.y, c0.z, c0.w);
      acc += proc4(e1, s1, t1, h1, b1, c1.x, c1.y, c1.z, c1.w);
      acc += proc4(e2, s2, t2, h2, b2, c2.x, c2.y, c2.z, c2.w);
      acc += proc4(e3, s3, t3, h3, b3, c3.x, c3.y, c3.z, c3.w);
    } else {
      int4 c0 = ((const int4*)cens)[i0];
      int4 c1 = ((const int4*)cens)[i1];
      int4 c2 = ((const int4*)cens)[i2];
      int4 c3 = ((const int4*)cens)[i3];
      acc += proc4(e0, s0, t0, h0, b0, c0.x, c0.y, c0.z, c0.w);
      acc += proc4(e1, s1, t1, h1, b1, c1.x, c1.y, c1.z, c1.w);
      acc += proc4(e2, s2, t2, h2, b2, c2.x, c2.y, c2.z, c2.w);
      acc += proc4(e3, s3, t3, h3, b3, c3.x, c3.y, c3.z, c3.w);
    }
  }
  // In-chunk tail.
  for (; i < end; i += NTHREADS) {
    float4 e = pe[i], s = ps[i], t = tg[i], h = th[i];
    int4 b = bid[i];
    int c0, c1, c2, c3;
    if (is8) {
      uchar4 c = ((const uchar4*)cens)[i];
      c0 = c.x; c1 = c.y; c2 = c.z; c3 = c.w;
    } else {
      int4 c = ((const int4*)cens)[i];
      c0 = c.x; c1 = c.y; c2 = c.z; c3 = c.w;
    }
    acc += proc4(e, s, t, h, b, c0, c1, c2, c3);
  }
  // Global remainder (none when nvec % gridDim == 0).
  for (int r = gridDim.x * vpb + blockIdx.x * NTHREADS + threadIdx.x; r < nvec;
       r += gridDim.x * NTHREADS) {
    float4 e = pe[r], s = ps[r], t = tg[r], h = th[r];
    int4 b = bid[r];
    int c0, c1, c2, c3;
    if (is8) {
      uchar4 c = ((const uchar4*)cens)[r];
      c0 = c.x; c1 = c.y; c2 = c.z; c3 = c.w;
    } else {
      int4 c = ((const int4*)cens)[r];
      c0 = c.x; c1 = c.y; c2 = c.z; c3 = c.w;
    }
    acc += proc4(e, s, t, h, b, c0, c1, c2, c3);
  }

  // ---- block reduction ----
  for (int off = 32; off > 0; off >>= 1) acc += __shfl_down(acc, off, 64);
  __shared__ float wsum[NTHREADS / 64];
  const int lane = threadIdx.x & 63;
  const int wid = threadIdx.x >> 6;
  if (lane == 0) wsum[wid] = acc;
  __syncthreads();

  // ---- last-block finalize (u32 ticket; no f64 CAS — R3 lesson) ----
  __shared__ int sdone;
  if (threadIdx.x == 0) {
    float b = 0.0f;
    for (int w = 0; w < NTHREADS / 64; ++w) b += wsum[w];
    partials[blockIdx.x] = b;   // plain store
    __threadfence();            // release
    unsigned t = atomicAdd(counter, 1u);
    sdone = (t == gridDim.x - 1);
  }
  __syncthreads();
  if (sdone) {
    __threadfence();  // acquire
    double dacc = 0.0;
    for (int i2 = threadIdx.x; i2 < (int)gridDim.x; i2 += NTHREADS) {
      // Native f32 atomic read (add 0), distinct addresses — device-coherent.
      dacc += (double)atomicAdd(&partials[i2], 0.0f);
    }
    for (int off = 32; off > 0; off >>= 1) dacc += __shfl_down(dacc, off, 64);
    __shared__ double dsum[NTHREADS / 64];
    if (lane == 0) dsum[wid] = dacc;
    __syncthreads();
    if (threadIdx.x == 0) {
      double s = 0.0;
      for (int w = 0; w < NTHREADS / 64; ++w) s += dsum[w];
      out[0] = (float)(s * inv_n);
    }
  }
}

extern "C" void kernel_launch(void* const* d_in, const int* in_sizes, int n_in,
                              void* d_out, int out_size, void* d_ws, size_t ws_size,
                              hipStream_t stream) {
  const float* pe = (const float*)d_in[0];
  const float* ps = (const float*)d_in[1];
  const float* tg = (const float*)d_in[2];
  const int* bid = (const int*)d_in[3];
  const void* cens = d_in[4];
  const float* th = (const float*)d_in[5];
  const int n = in_sizes[0];
  const int nvec = n / 4;

  float* partials = (float*)d_ws;
  unsigned* counter = (unsigned*)((char*)d_ws + NBLOCKS * sizeof(float));

  hipMemsetAsync(counter, 0, sizeof(unsigned), stream);

  dualhead_fused<<<NBLOCKS, NTHREADS, 0, stream>>>(
      (const float4*)pe, (const float4*)ps, (const float4*)tg,
      (const int4*)bid, cens, (const float4*)th, partials, counter,
      (float*)d_out, nvec, 1.0 / (double)n);
}

// Round 8
// 72.550 us; speedup vs baseline: 2.3943x; 2.3943x over previous
//
#include <hip/hip_runtime.h>

#define NBLOCKS 2048
#define NTHREADS 256

// Per-sample loss. DELTA = 1.0, CENSORING_WEIGHT = 1.0.
__device__ __forceinline__ float per_sample(float pe, float ps, float tg,
                                            float th, int bid, int cen) {
  float pred = (bid == 0) ? pe : ps;
  float d = fmaxf(th - pred, 0.0f);
  float closs = d * d;
  float ae = fabsf(pred - tg);
  float q = fminf(ae, 1.0f);
  float hub = 0.5f * q * q + (ae - q);
  return cen ? closs : hub;
}

__device__ __forceinline__ float proc4(const float4& e, const float4& s,
                                       const float4& t, const float4& h,
                                       const int4& b, int c0, int c1, int c2,
                                       int c3) {
  float a = per_sample(e.x, s.x, t.x, h.x, b.x, c0);
  a += per_sample(e.y, s.y, t.y, h.y, b.y, c1);
  a += per_sample(e.z, s.z, t.z, h.z, b.z, c2);
  a += per_sample(e.w, s.w, t.w, h.w, b.w, c3);
  return a;
}

// FINAL STRUCTURE (R5, best: 72.1 us bench, ~5.3 TB/s touched-bytes):
//  - 2048 chunked contiguous per-block ranges (DRAM row locality, R4 +15%)
//  - unroll-4 ARRAY-MAJOR groups at stride NTHREADS: lane-contiguous 1KB
//    segments per load instruction, 4KB burst per array (R5 +2.6%;
//    R6 lesson: thread-consecutive float4 pairs break coalescing, -40%)
//  - in-kernel ballot layout probe for is_censored (R3/R4, frees a node)
//  - separate 1-block final_reduce kernel. R3+R7 lesson: single-kernel
//    fusion via device-scope fences costs ~+90us (per-block __threadfence
//    = L2 writeback/inv, ~44ns serialized x 2048); a kernel boundary is
//    ONE implicit device fence and is ~20x cheaper.
__global__ __launch_bounds__(NTHREADS, 4) void dualhead_main(
    const float4* __restrict__ pe, const float4* __restrict__ ps,
    const float4* __restrict__ tg, const int4* __restrict__ bid,
    const void* __restrict__ cens, const float4* __restrict__ th,
    float* __restrict__ partials, int nvec) {
  // Layout probe: int32 {0,1} => high 3 bytes of every dword are 0.
  unsigned probe = ((const unsigned*)cens)[threadIdx.x & 63];
  const bool is8 = __ballot((probe & 0xFFFFFF00u) != 0) != 0ULL;

  const int vpb = nvec / gridDim.x;  // vec4 elems per block (2048 for N=16M)
  const int base = blockIdx.x * vpb;
  const int end = base + vpb;
  float acc = 0.0f;
  int i = base + threadIdx.x;

  // Unroll-4 group: 24 loads in flight, 4KB contiguity per array.
  for (; i + 3 * NTHREADS < end; i += 4 * NTHREADS) {
    const int i0 = i, i1 = i + NTHREADS, i2 = i + 2 * NTHREADS,
              i3 = i + 3 * NTHREADS;
    float4 e0 = pe[i0], e1 = pe[i1], e2 = pe[i2], e3 = pe[i3];
    float4 s0 = ps[i0], s1 = ps[i1], s2 = ps[i2], s3 = ps[i3];
    float4 t0 = tg[i0], t1 = tg[i1], t2 = tg[i2], t3 = tg[i3];
    float4 h0 = th[i0], h1 = th[i1], h2 = th[i2], h3 = th[i3];
    int4 b0 = bid[i0], b1 = bid[i1], b2 = bid[i2], b3 = bid[i3];
    if (is8) {
      uchar4 c0 = ((const uchar4*)cens)[i0];
      uchar4 c1 = ((const uchar4*)cens)[i1];
      uchar4 c2 = ((const uchar4*)cens)[i2];
      uchar4 c3 = ((const uchar4*)cens)[i3];
      acc += proc4(e0, s0, t0, h0, b0, c0.x, c0.y, c0.z, c0.w);
      acc += proc4(e1, s1, t1, h1, b1, c1.x, c1.y, c1.z, c1.w);
      acc += proc4(e2, s2, t2, h2, b2, c2.x, c2.y, c2.z, c2.w);
      acc += proc4(e3, s3, t3, h3, b3, c3.x, c3.y, c3.z, c3.w);
    } else {
      int4 c0 = ((const int4*)cens)[i0];
      int4 c1 = ((const int4*)cens)[i1];
      int4 c2 = ((const int4*)cens)[i2];
      int4 c3 = ((const int4*)cens)[i3];
      acc += proc4(e0, s0, t0, h0, b0, c0.x, c0.y, c0.z, c0.w);
      acc += proc4(e1, s1, t1, h1, b1, c1.x, c1.y, c1.z, c1.w);
      acc += proc4(e2, s2, t2, h2, b2, c2.x, c2.y, c2.z, c2.w);
      acc += proc4(e3, s3, t3, h3, b3, c3.x, c3.y, c3.z, c3.w);
    }
  }
  // In-chunk tail (none for N=16M).
  for (; i < end; i += NTHREADS) {
    float4 e = pe[i], s = ps[i], t = tg[i], h = th[i];
    int4 b = bid[i];
    int c0, c1, c2, c3;
    if (is8) {
      uchar4 c = ((const uchar4*)cens)[i];
      c0 = c.x; c1 = c.y; c2 = c.z; c3 = c.w;
    } else {
      int4 c = ((const int4*)cens)[i];
      c0 = c.x; c1 = c.y; c2 = c.z; c3 = c.w;
    }
    acc += proc4(e, s, t, h, b, c0, c1, c2, c3);
  }
  // Global remainder (none when nvec % gridDim == 0).
  for (int r = gridDim.x * vpb + blockIdx.x * NTHREADS + threadIdx.x; r < nvec;
       r += gridDim.x * NTHREADS) {
    float4 e = pe[r], s = ps[r], t = tg[r], h = th[r];
    int4 b = bid[r];
    int c0, c1, c2, c3;
    if (is8) {
      uchar4 c = ((const uchar4*)cens)[r];
      c0 = c.x; c1 = c.y; c2 = c.z; c3 = c.w;
    } else {
      int4 c = ((const int4*)cens)[r];
      c0 = c.x; c1 = c.y; c2 = c.z; c3 = c.w;
    }
    acc += proc4(e, s, t, h, b, c0, c1, c2, c3);
  }

  // Block reduction -> plain store (no device atomics, no fences).
  for (int off = 32; off > 0; off >>= 1) acc += __shfl_down(acc, off, 64);
  __shared__ float wsum[NTHREADS / 64];
  const int lane = threadIdx.x & 63;
  const int wid = threadIdx.x >> 6;
  if (lane == 0) wsum[wid] = acc;
  __syncthreads();
  if (threadIdx.x == 0) {
    float b = 0.0f;
    for (int w = 0; w < NTHREADS / 64; ++w) b += wsum[w];
    partials[blockIdx.x] = b;
  }
}

__global__ void final_reduce(const float4* __restrict__ partials, int nvec4,
                             float* __restrict__ out, double inv_n) {
  double acc = 0.0;
  for (int i = threadIdx.x; i < nvec4; i += blockDim.x) {
    float4 p = partials[i];
    acc += (double)p.x + (double)p.y + (double)p.z + (double)p.w;
  }
  for (int off = 32; off > 0; off >>= 1) acc += __shfl_down(acc, off, 64);
  __shared__ double wsum[256 / 64];
  const int lane = threadIdx.x & 63;
  const int wid = threadIdx.x >> 6;
  if (lane == 0) wsum[wid] = acc;
  __syncthreads();
  if (threadIdx.x == 0) {
    double s = 0.0;
    for (int w = 0; w < 4; ++w) s += wsum[w];
    out[0] = (float)(s * inv_n);
  }
}

extern "C" void kernel_launch(void* const* d_in, const int* in_sizes, int n_in,
                              void* d_out, int out_size, void* d_ws, size_t ws_size,
                              hipStream_t stream) {
  const float* pe = (const float*)d_in[0];
  const float* ps = (const float*)d_in[1];
  const float* tg = (const float*)d_in[2];
  const int* bid = (const int*)d_in[3];
  const void* cens = d_in[4];
  const float* th = (const float*)d_in[5];
  const int n = in_sizes[0];
  const int nvec = n / 4;

  float* partials = (float*)d_ws;

  dualhead_main<<<NBLOCKS, NTHREADS, 0, stream>>>(
      (const float4*)pe, (const float4*)ps, (const float4*)tg,
      (const int4*)bid, cens, (const float4*)th, partials, nvec);
  final_reduce<<<1, 256, 0, stream>>>((const float4*)partials, NBLOCKS / 4,
                                      (float*)d_out, 1.0 / (double)n);
}